// Round 1
// baseline (375.883 us; speedup 1.0000x reference)
//
#include <hip/hip_runtime.h>

typedef unsigned short ushort_t;
typedef __attribute__((ext_vector_type(8))) short bf16x8;
typedef __attribute__((ext_vector_type(4))) float f32x4;

__device__ __forceinline__ unsigned short f2bf(float f) {
  union { float f; unsigned int u; } v; v.f = f;
  unsigned int r = v.u + 0x7FFFu + ((v.u >> 16) & 1u);
  return (unsigned short)(r >> 16);
}

__device__ __forceinline__ void gl_lds16(const void* gsrc, void* ldst) {
  __builtin_amdgcn_global_load_lds(
      (const __attribute__((address_space(1))) void*)gsrc,
      (__attribute__((address_space(3))) void*)ldst, 16, 0, 0);
}

// ---------------------------------------------------------------------------
// K1: fold Wc = w128 @ wv  (128x256), cb = w128 @ bv (128)
// ---------------------------------------------------------------------------
__global__ __launch_bounds__(256) void k1_fold(
    const float* __restrict__ w128, const float* __restrict__ wv,
    const float* __restrict__ bv, float* __restrict__ Wc, float* __restrict__ cb)
{
  const int o = blockIdx.x, ci = threadIdx.x;
  float acc = 0.f;
  for (int co = 0; co < 256; co++) acc += w128[o*256 + co] * wv[co*256 + ci];
  Wc[o*256 + ci] = acc;
  if (ci == 0) {
    float a = 0.f;
    for (int co = 0; co < 256; co++) a += w128[o*256 + co] * bv[co];
    cb[o] = a;
  }
}

// ---------------------------------------------------------------------------
// K2: features.  grid (256 pixel-tiles of 64, 10 out-chunks of 64)
//   oc 0..3 -> Q (wq,bq) bf16;  oc 4..7 -> K (wk,bk) bf16;  oc 8..9 -> V (Wc,cb) f32
//   Q/K stored row-major [pixel][256] bf16; V stored [src][b][o][hw] f32.
// ---------------------------------------------------------------------------
__global__ __launch_bounds__(256) void k2_features(
    const float* __restrict__ x4, const float* __restrict__ x3,
    const float* __restrict__ wq, const float* __restrict__ bq,
    const float* __restrict__ wk, const float* __restrict__ bk,
    const float* __restrict__ Wc, const float* __restrict__ cb,
    ushort_t* __restrict__ Qb, ushort_t* __restrict__ Kb, float* __restrict__ V)
{
  __shared__ float xt[64*64];     // [c][px]
  __shared__ float wt[64*65];     // [o][c] padded

  const int tid = threadIdx.x;
  const int P0 = blockIdx.x * 64;                 // global pixel base
  const int src = P0 >> 13, rem = P0 & 8191;
  const int bb = rem >> 10, hw0 = rem & 1023;     // 64-tiles never straddle b
  const float* xp = (src ? x3 : x4) + bb*262144 + hw0;

  const int oc = blockIdx.y;
  const float* W; const float* bias; int obase, mode;
  if (oc < 4)      { W = wq; bias = bq; obase = oc*64;     mode = 0; }
  else if (oc < 8) { W = wk; bias = bk; obase = (oc-4)*64; mode = 1; }
  else             { W = Wc; bias = cb; obase = (oc-8)*64; mode = 2; }

  const int tx = tid >> 4, ty = tid & 15;         // px group / o group
  float acc[4][4] = {};                           // [px_i][o_j]

  for (int cc = 0; cc < 256; cc += 64) {
    __syncthreads();
    for (int t = tid; t < 4096; t += 256) {
      const int cl = t >> 6, u = t & 63;
      xt[cl*64 + u] = xp[(cc + cl)*1024 + u];
      wt[cl*65 + u] = W[(obase + cl)*256 + cc + u];
    }
    __syncthreads();
    for (int c = 0; c < 64; c++) {
      const float4 xv = *(const float4*)&xt[c*64 + tx*4];
      #pragma unroll
      for (int j = 0; j < 4; j++) {
        const float wv_ = wt[(ty*4 + j)*65 + c];
        acc[0][j] += xv.x * wv_;
        acc[1][j] += xv.y * wv_;
        acc[2][j] += xv.z * wv_;
        acc[3][j] += xv.w * wv_;
      }
    }
  }

  if (mode < 2) {
    ushort_t* dst = (mode == 0) ? Qb : Kb;
    #pragma unroll
    for (int i = 0; i < 4; i++) {
      const int p = P0 + tx*4 + i;
      ushort4 pk;
      pk.x = f2bf(acc[i][0] + bias[obase + ty*4 + 0]);
      pk.y = f2bf(acc[i][1] + bias[obase + ty*4 + 1]);
      pk.z = f2bf(acc[i][2] + bias[obase + ty*4 + 2]);
      pk.w = f2bf(acc[i][3] + bias[obase + ty*4 + 3]);
      *(ushort4*)&dst[(size_t)p*256 + obase + ty*4] = pk;
    }
  } else {
    #pragma unroll
    for (int j = 0; j < 4; j++) {
      const int o = obase + ty*4 + j;
      const float bo = bias[o];
      float4 v;
      v.x = acc[0][j] + bo; v.y = acc[1][j] + bo;
      v.z = acc[2][j] + bo; v.w = acc[3][j] + bo;
      *(float4*)&V[((size_t)((src*8 + bb)*128 + o) << 10) + hw0 + tx*4] = v;
    }
  }
}

// ---------------------------------------------------------------------------
// K3: streaming S = Q K^T with per-row max over each 128-col tile.
//   128x128 tile per block (256 thr / 4 waves, each 64x64 via 4x4 MFMA 16x16x32).
//   XOR-swizzled LDS (chunk s holds global chunk s^(m&7)) -> balanced banks for
//   both global_load_lds staging and bf16x8 fragment reads.
//   Pt layout: [col_tile(128)][row(16384)]
// ---------------------------------------------------------------------------
__global__ __launch_bounds__(256) void k3_smax(
    const ushort_t* __restrict__ Qb, const ushort_t* __restrict__ Kb,
    float* __restrict__ Pt)
{
  __shared__ ushort_t As[128*64];
  __shared__ ushort_t Bs[128*64];
  __shared__ float smax[128*2];

  const int tid = threadIdx.x;
  const int ct = blockIdx.x >> 7;
  const int rt = blockIdx.x & 127;
  const int row0 = rt << 7, col0 = ct << 7;

  const int w = tid >> 6, lane = tid & 63;
  const int wm = w >> 1, wn = w & 1;
  const int lrow = lane >> 3, lslot = lane & 7;
  const int mrow = lane & 15, quad = lane >> 4;

  f32x4 acc[4][4];
  #pragma unroll
  for (int i = 0; i < 4; i++)
    #pragma unroll
    for (int j = 0; j < 4; j++)
      acc[i][j] = (f32x4){0.f, 0.f, 0.f, 0.f};

  for (int kk = 0; kk < 256; kk += 64) {
    #pragma unroll
    for (int q = 0; q < 4; q++) {
      const int r0 = w*32 + q*8;            // wave-uniform LDS row base
      const int m  = r0 + lrow;
      const int g  = lslot ^ (m & 7);       // source chunk for swizzled slot
      gl_lds16(Qb + (size_t)(row0 + m)*256 + kk + g*8, &As[r0*64]);
      gl_lds16(Kb + (size_t)(col0 + m)*256 + kk + g*8, &Bs[r0*64]);
    }
    asm volatile("s_waitcnt vmcnt(0)" ::: "memory");
    __syncthreads();

    #pragma unroll
    for (int kc = 0; kc < 2; kc++) {
      bf16x8 af[4], bfv[4];
      const int cg = kc*4 + quad;           // 16B k-chunk index 0..7
      #pragma unroll
      for (int i = 0; i < 4; i++) {
        const int m = wm*64 + i*16 + mrow;
        af[i]  = *(const bf16x8*)&As[m*64 + (cg ^ (m & 7))*8];
        const int n = wn*64 + i*16 + mrow;
        bfv[i] = *(const bf16x8*)&Bs[n*64 + (cg ^ (n & 7))*8];
      }
      #pragma unroll
      for (int i = 0; i < 4; i++)
        #pragma unroll
        for (int j = 0; j < 4; j++)
          acc[i][j] = __builtin_amdgcn_mfma_f32_16x16x32_bf16(af[i], bfv[j], acc[i][j], 0, 0, 0);
    }
    __syncthreads();
  }

  // row-max epilogue: C/D layout col=lane&15, row=quad*4+reg (m89-verified)
  #pragma unroll
  for (int i = 0; i < 4; i++) {
    #pragma unroll
    for (int r = 0; r < 4; r++) {
      float v = acc[i][0][r];
      v = fmaxf(v, acc[i][1][r]);
      v = fmaxf(v, acc[i][2][r]);
      v = fmaxf(v, acc[i][3][r]);
      v = fmaxf(v, __shfl_xor(v, 1));
      v = fmaxf(v, __shfl_xor(v, 2));
      v = fmaxf(v, __shfl_xor(v, 4));
      v = fmaxf(v, __shfl_xor(v, 8));
      if (mrow == 0) smax[(wm*64 + i*16 + quad*4 + r)*2 + wn] = v;
    }
  }
  __syncthreads();
  if (tid < 128)
    Pt[(size_t)ct*16384 + row0 + tid] = fmaxf(smax[tid*2], smax[tid*2 + 1]);
}

// ---------------------------------------------------------------------------
// K4: reduce partial maxes -> m_a/m_b; softmax over hw per (qset, b) -> gates.
//   G[0]=g_aa G[1]=g_ab G[2]=g_ba G[3]=g_bb, each (8,1024).
// ---------------------------------------------------------------------------
__global__ __launch_bounds__(1024) void k4_gates(
    const float* __restrict__ Pt, float* __restrict__ G)
{
  __shared__ float red[1024];
  const int tid = threadIdx.x;
  const int qset = blockIdx.x >> 3, b = blockIdx.x & 7;
  const int i = qset*8192 + b*1024 + tid;

  float ma = 0.f, mb = 0.f;
  for (int blk = 0; blk < 16; blk++) {
    float mx = -3.4e38f;
    #pragma unroll
    for (int t = 0; t < 8; t++) mx = fmaxf(mx, Pt[(size_t)(blk*8 + t)*16384 + i]);
    if (blk < 8) ma += mx; else mb += mx;
  }
  const float sc = 0.125f * 0.0625f;   // mean over 8 batches * 1/sqrt(256)
  const float la = ma * sc, lb = mb * sc;

  red[tid] = la; __syncthreads();
  for (int s = 512; s > 0; s >>= 1) { if (tid < s) red[tid] = fmaxf(red[tid], red[tid+s]); __syncthreads(); }
  const float Ma = red[0]; __syncthreads();
  const float ea = expf(la - Ma);
  red[tid] = ea; __syncthreads();
  for (int s = 512; s > 0; s >>= 1) { if (tid < s) red[tid] += red[tid+s]; __syncthreads(); }
  const float ga = ea / red[0]; __syncthreads();

  red[tid] = lb; __syncthreads();
  for (int s = 512; s > 0; s >>= 1) { if (tid < s) red[tid] = fmaxf(red[tid], red[tid+s]); __syncthreads(); }
  const float Mb = red[0]; __syncthreads();
  const float eb = expf(lb - Mb);
  red[tid] = eb; __syncthreads();
  for (int s = 512; s > 0; s >>= 1) { if (tid < s) red[tid] += red[tid+s]; __syncthreads(); }
  const float gb = eb / red[0];

  G[(size_t)(qset*2 + 0)*8192 + b*1024 + tid] = ga;
  G[(size_t)(qset*2 + 1)*8192 + b*1024 + tid] = gb;
}

// ---------------------------------------------------------------------------
// K5: out[b][ch][hw] = gate * V + b128.  ch blocks: [x34|a_x4|x43|b_x3]
// ---------------------------------------------------------------------------
__global__ __launch_bounds__(256) void k5_out(
    const float* __restrict__ V, const float* __restrict__ G,
    const float* __restrict__ b128, float* __restrict__ out)
{
  const int idx = blockIdx.x*256 + threadIdx.x;
  const int flat = idx << 2;
  const int hw = flat & 1023;
  const int ch = (flat >> 10) & 511;
  const int b  = flat >> 19;
  const int blk = ch >> 7, o = ch & 127;
  const int gidx = (blk == 0) ? 2 : (blk == 1) ? 0 : (blk == 2) ? 1 : 3;
  const int src = (blk >= 2) ? 1 : 0;

  const float4 v = *(const float4*)&V[((size_t)((src*8 + b)*128 + o) << 10) + hw];
  const float4 g = *(const float4*)&G[(size_t)gidx*8192 + b*1024 + hw];
  const float bias = b128[o];
  float4 r;
  r.x = g.x*v.x + bias; r.y = g.y*v.y + bias;
  r.z = g.z*v.z + bias; r.w = g.w*v.w + bias;
  *(float4*)&out[flat] = r;
}

// ---------------------------------------------------------------------------
extern "C" void kernel_launch(void* const* d_in, const int* in_sizes, int n_in,
                              void* d_out, int out_size, void* d_ws, size_t ws_size,
                              hipStream_t stream)
{
  const float* x4   = (const float*)d_in[0];
  const float* x3   = (const float*)d_in[1];
  const float* wq   = (const float*)d_in[2];
  const float* bq   = (const float*)d_in[3];
  const float* wk   = (const float*)d_in[4];
  const float* bk   = (const float*)d_in[5];
  const float* wv   = (const float*)d_in[6];
  const float* bv   = (const float*)d_in[7];
  const float* w128 = (const float*)d_in[8];
  const float* b128 = (const float*)d_in[9];
  float* out = (float*)d_out;

  char* ws = (char*)d_ws;
  float*    Wc = (float*)ws;     ws += (size_t)128*256*4;       // 131072
  float*    cb = (float*)ws;     ws += 512;
  ushort_t* Qb = (ushort_t*)ws;  ws += (size_t)16384*256*2;     // 8 MB
  ushort_t* Kb = (ushort_t*)ws;  ws += (size_t)16384*256*2;     // 8 MB
  float*    V  = (float*)ws;     ws += (size_t)2*8*128*1024*4;  // 8 MB
  float*    Pt = (float*)ws;     ws += (size_t)128*16384*4;     // 8 MB
  float*    G  = (float*)ws;                                    // 128 KB

  k1_fold    <<<128,           256, 0, stream>>>(w128, wv, bv, Wc, cb);
  k2_features<<<dim3(256, 10), 256, 0, stream>>>(x4, x3, wq, bq, wk, bk, Wc, cb, Qb, Kb, V);
  k3_smax    <<<16384,         256, 0, stream>>>(Qb, Kb, Pt);
  k4_gates   <<<16,           1024, 0, stream>>>(Pt, G);
  k5_out     <<<4096,          256, 0, stream>>>(V, G, b128, out);
}

// Round 2
// 288.725 us; speedup vs baseline: 1.3019x; 1.3019x over previous
//
#include <hip/hip_runtime.h>

typedef unsigned short ushort_t;
typedef __attribute__((ext_vector_type(8))) short bf16x8;
typedef __attribute__((ext_vector_type(4))) float f32x4;

__device__ __forceinline__ unsigned short f2bf(float f) {
  union { float f; unsigned int u; } v; v.f = f;
  unsigned int r = v.u + 0x7FFFu + ((v.u >> 16) & 1u);
  return (unsigned short)(r >> 16);
}

__device__ __forceinline__ void gl_lds16(const void* gsrc, void* ldst) {
  __builtin_amdgcn_global_load_lds(
      (const __attribute__((address_space(1))) void*)gsrc,
      (__attribute__((address_space(3))) void*)ldst, 16, 0, 0);
}

// ---------------------------------------------------------------------------
// K1: build fragment-major bf16 weight bank Wf[640][256] (Q=wq, K=wk, V=w128@wv)
//     + bias_all[640] (bq, bk, w128@bv).
// Fragment-major: chunk = (oc>>4)*8 + (ci>>5); lane = ((ci>>3)&3)*16 + (oc&15);
//                 elem = ci&7  -> flat = chunk*512 + lane*8 + elem
// ---------------------------------------------------------------------------
__global__ __launch_bounds__(256) void k1_weights(
    const float* __restrict__ wq, const float* __restrict__ bq,
    const float* __restrict__ wk, const float* __restrict__ bk,
    const float* __restrict__ wv, const float* __restrict__ bv,
    const float* __restrict__ w128, const float* __restrict__ b128u,
    ushort_t* __restrict__ Wf, float* __restrict__ bias_all)
{
  const int oc = blockIdx.x;   // 0..639
  const int ci = threadIdx.x;  // 0..255
  float v;
  if (oc < 256)      v = wq[oc*256 + ci];
  else if (oc < 512) v = wk[(oc-256)*256 + ci];
  else {
    float a = 0.f;
    const float* wr = w128 + (size_t)(oc-512)*256;
    for (int co = 0; co < 256; co++) a += wr[co] * wv[co*256 + ci];
    v = a;
  }
  const int idx = (((oc>>4)*8 + (ci>>5))<<9) + ((((ci>>3)&3)*16 + (oc&15))<<3) + (ci&7);
  Wf[idx] = f2bf(v);
  if (ci == 0) {
    float bz;
    if (oc < 256) bz = bq[oc];
    else if (oc < 512) bz = bk[oc-256];
    else {
      float a = 0.f;
      const float* wr = w128 + (size_t)(oc-512)*256;
      for (int co = 0; co < 256; co++) a += wr[co] * bv[co];
      bz = a;
    }
    bias_all[oc] = bz;
  }
  (void)b128u;
}

// ---------------------------------------------------------------------------
// K2: MFMA feature GEMM. Grid 256 blocks = 64-pixel tiles. 4 waves.
//   A (M) = weights (frag-major via gl_lds, double-buffered per 64-oc tile)
//   B (N) = x-pixels (transposed+bf16-cast into LDS fragments once)
//   ot 0..3 -> Qf, 4..7 -> Kf (bf16 frag-major), 8..9 -> V fp32 [src*8+b][oc][hw]
// ---------------------------------------------------------------------------
__global__ __launch_bounds__(256) void k2_features(
    const float* __restrict__ x4, const float* __restrict__ x3,
    const ushort_t* __restrict__ Wf, const float* __restrict__ bias_all,
    ushort_t* __restrict__ Qf, ushort_t* __restrict__ Kf, float* __restrict__ V)
{
  __shared__ ushort_t Af[32*512];      // 32 chunks (4 pxgrp x 8 kb) = 32 KB
  __shared__ ushort_t Wl[2][32*512];   // 2 x 32 KB
  __shared__ ushort_t Lt[64*72];       // repack buffer (px-major, padded)

  const int tid = threadIdx.x;
  const int w = tid >> 6, lane = tid & 63;
  const int mrow = lane & 15, quad = lane >> 4;

  const int px0 = blockIdx.x * 64;
  const int src = px0 >> 13, b = (px0 >> 10) & 7, hw0 = px0 & 1023;
  const float* xp = (src ? x3 : x4) + (size_t)b*262144;

  // stage W tile for ot=0
  for (int kb = 0; kb < 8; kb++)
    gl_lds16(Wf + ((size_t)((0*4 + w)*8 + kb)<<9) + lane*8, &Wl[0][(w*8+kb)*512]);

  // stage A: wave w stages chunks (pxgrp=w, kb=0..7); lane holds px=mrow, ch=quad*8+j
  {
    const int hw = hw0 + w*16 + mrow;
    for (int kb = 0; kb < 8; kb++) {
      const int ch0 = kb*32 + quad*8;
      bf16x8 pk;
      #pragma unroll
      for (int j = 0; j < 8; j++)
        ((ushort_t*)&pk)[j] = f2bf(xp[(size_t)(ch0 + j)*1024 + hw]);
      *(bf16x8*)&Af[(w*8 + kb)*512 + lane*8] = pk;
    }
  }
  __syncthreads();   // Af visible; Wl[0] drained by barrier's vmcnt(0)

  for (int ot = 0; ot < 10; ot++) {
    const int nbuf = (ot+1) & 1, cbuf = ot & 1;
    if (ot < 9)
      for (int kb = 0; kb < 8; kb++)
        gl_lds16(Wf + ((size_t)(((ot+1)*4 + w)*8 + kb)<<9) + lane*8,
                 &Wl[nbuf][(w*8+kb)*512]);
    // ensure Wl[cbuf] (8 oldest before the 8 just issued) has landed
    asm volatile("s_waitcnt vmcnt(8)" ::: "memory");

    f32x4 acc[4];
    #pragma unroll
    for (int lg = 0; lg < 4; lg++) acc[lg] = (f32x4){0.f,0.f,0.f,0.f};
    #pragma unroll
    for (int kb = 0; kb < 8; kb++) {
      const bf16x8 a = *(const bf16x8*)&Wl[cbuf][(w*8 + kb)*512 + lane*8];
      #pragma unroll
      for (int lg = 0; lg < 4; lg++) {
        const bf16x8 bx = *(const bf16x8*)&Af[(lg*8 + kb)*512 + lane*8];
        acc[lg] = __builtin_amdgcn_mfma_f32_16x16x32_bf16(a, bx, acc[lg], 0, 0, 0);
      }
    }
    // C/D: col(lane&15)=px-local within lg*16 group, row(quad*4+r)=oc-local in wave strip
    const int ocl = w*16 + quad*4;
    const float4 bias4 = *(const float4*)&bias_all[ot*64 + ocl];

    if (ot < 8) {
      __syncthreads();   // Lt free
      #pragma unroll
      for (int lg = 0; lg < 4; lg++) {
        const int px = lg*16 + mrow;
        ushort4 pk;
        pk.x = f2bf(acc[lg][0] + bias4.x);
        pk.y = f2bf(acc[lg][1] + bias4.y);
        pk.z = f2bf(acc[lg][2] + bias4.z);
        pk.w = f2bf(acc[lg][3] + bias4.w);
        *(ushort4*)&Lt[px*72 + ocl] = pk;
      }
      __syncthreads();
      // wave w emits frags (pxgrp = w, kbl = 0,1) in frag-major layout
      ushort_t* dst = (ot < 4) ? Qf : Kf;
      const int kbg0 = (ot & 3)*2;
      #pragma unroll
      for (int kbl = 0; kbl < 2; kbl++) {
        const bf16x8 vv = *(const bf16x8*)&Lt[(w*16 + mrow)*72 + kbl*32 + quad*8];
        const size_t chunk = ((size_t)((px0>>4) + w)*8 + kbg0 + kbl) << 9;
        *(bf16x8*)&dst[chunk + lane*8] = vv;
      }
    } else {
      const int ocv0 = (ot-8)*64 + ocl;
      float* vb = V + (((size_t)(src*8 + b)*128) << 10) + hw0;
      #pragma unroll
      for (int lg = 0; lg < 4; lg++) {
        vb[(size_t)(ocv0+0)*1024 + lg*16 + mrow] = acc[lg][0] + bias4.x;
        vb[(size_t)(ocv0+1)*1024 + lg*16 + mrow] = acc[lg][1] + bias4.y;
        vb[(size_t)(ocv0+2)*1024 + lg*16 + mrow] = acc[lg][2] + bias4.z;
        vb[(size_t)(ocv0+3)*1024 + lg*16 + mrow] = acc[lg][3] + bias4.w;
      }
    }
  }
}

// ---------------------------------------------------------------------------
// K3: S = Q K^T row-max, 128x128 tile, 4 waves (2x2), K staged via gl_lds
//     (double-buffered, 1 barrier/K-step), Q A-frags loaded direct global->VGPR.
// ---------------------------------------------------------------------------
__global__ __launch_bounds__(256, 3) void k3_smax(
    const ushort_t* __restrict__ Qf, const ushort_t* __restrict__ Kf,
    float* __restrict__ Pt)
{
  __shared__ ushort_t Kl[2][8192];   // 2 x 16 KB (16 chunks of 1 KB each)

  const int tid = threadIdx.x;
  const int ct = blockIdx.x >> 7, rt = blockIdx.x & 127;
  const int w = tid >> 6, lane = tid & 63;
  const int wm = w >> 1, wn = w & 1;
  const int mrow = lane & 15, quad = lane >> 4;

  const int rg0 = rt*8 + wm*4;   // this wave's 4 row-grps
  const int cg0 = ct*8;          // block's 8 col-grps

  // prologue: stage K chunks for t=0 (kb 0,1); wave w stages chunks w*4..w*4+3
  #pragma unroll
  for (int q = 0; q < 4; q++) {
    const int c = w*4 + q;       // c = gl*2 + kbl
    gl_lds16(Kf + ((size_t)((cg0 + (c>>1))*8 + (c&1))<<9) + lane*8, &Kl[0][c*512]);
  }

  f32x4 acc[4][4];
  #pragma unroll
  for (int i = 0; i < 4; i++)
    #pragma unroll
    for (int j = 0; j < 4; j++)
      acc[i][j] = (f32x4){0.f, 0.f, 0.f, 0.f};

  for (int t = 0; t < 4; t++) {
    __syncthreads();   // barrier's vmcnt(0) drains stage(t) (issued a full phase ago)
    if (t < 3) {
      #pragma unroll
      for (int q = 0; q < 4; q++) {
        const int c = w*4 + q;
        gl_lds16(Kf + ((size_t)((cg0 + (c>>1))*8 + ((t+1)*2 + (c&1)))<<9) + lane*8,
                 &Kl[(t+1)&1][c*512]);
      }
    }
    const int cur = t & 1;
    #pragma unroll
    for (int kc = 0; kc < 2; kc++) {
      const int kb = t*2 + kc;
      bf16x8 af[4], bfv[4];
      #pragma unroll
      for (int i = 0; i < 4; i++)
        af[i] = *(const bf16x8*)&Qf[((size_t)((rg0 + i)*8 + kb)<<9) + lane*8];
      #pragma unroll
      for (int j = 0; j < 4; j++)
        bfv[j] = *(const bf16x8*)&Kl[cur][((wn*4 + j)*2 + kc)*512 + lane*8];
      #pragma unroll
      for (int i = 0; i < 4; i++)
        #pragma unroll
        for (int j = 0; j < 4; j++)
          acc[i][j] = __builtin_amdgcn_mfma_f32_16x16x32_bf16(af[i], bfv[j], acc[i][j], 0, 0, 0);
    }
  }

  // row-max epilogue; smax overlays Kl[0] (not read during t=3)
  float* smax = (float*)&Kl[0][0];
  #pragma unroll
  for (int i = 0; i < 4; i++) {
    #pragma unroll
    for (int r = 0; r < 4; r++) {
      float v = acc[i][0][r];
      v = fmaxf(v, acc[i][1][r]);
      v = fmaxf(v, acc[i][2][r]);
      v = fmaxf(v, acc[i][3][r]);
      v = fmaxf(v, __shfl_xor(v, 1));
      v = fmaxf(v, __shfl_xor(v, 2));
      v = fmaxf(v, __shfl_xor(v, 4));
      v = fmaxf(v, __shfl_xor(v, 8));
      if (mrow == 0) smax[(wm*64 + i*16 + quad*4 + r)*2 + wn] = v;
    }
  }
  __syncthreads();
  if (tid < 128)
    Pt[(size_t)ct*16384 + (rt<<7) + tid] = fmaxf(smax[tid*2], smax[tid*2 + 1]);
}

// ---------------------------------------------------------------------------
// K4a: reduce Pt[128][16384] -> logits m2[2][16384] (mean over 8 batch-maxes, scaled)
// ---------------------------------------------------------------------------
__global__ __launch_bounds__(256) void k4a_reduce(
    const float* __restrict__ Pt, float* __restrict__ m2)
{
  const int i = blockIdx.x*256 + threadIdx.x;   // grid 64 -> 16384 rows
  float ma = 0.f, mb = 0.f;
  for (int g = 0; g < 16; g++) {
    float mx = -3.4e38f;
    #pragma unroll
    for (int t = 0; t < 8; t++) mx = fmaxf(mx, Pt[(size_t)(g*8 + t)*16384 + i]);
    if (g < 8) ma += mx; else mb += mx;
  }
  const float sc = 0.125f * 0.0625f;   // mean over 8 batches * 1/sqrt(256)
  m2[i] = ma * sc;
  m2[16384 + i] = mb * sc;
}

// ---------------------------------------------------------------------------
// K4b: softmax over hw per (qset, b) -> gates G[4][8][1024]
// ---------------------------------------------------------------------------
__global__ __launch_bounds__(1024) void k4b_gates(
    const float* __restrict__ m2, float* __restrict__ G)
{
  __shared__ float red[1024];
  const int tid = threadIdx.x;
  const int qset = blockIdx.x >> 3, b = blockIdx.x & 7;
  const int i = qset*8192 + b*1024 + tid;
  const float la = m2[i], lb = m2[16384 + i];

  red[tid] = la; __syncthreads();
  for (int s = 512; s > 0; s >>= 1) { if (tid < s) red[tid] = fmaxf(red[tid], red[tid+s]); __syncthreads(); }
  const float Ma = red[0]; __syncthreads();
  const float ea = expf(la - Ma);
  red[tid] = ea; __syncthreads();
  for (int s = 512; s > 0; s >>= 1) { if (tid < s) red[tid] += red[tid+s]; __syncthreads(); }
  const float ga = ea / red[0]; __syncthreads();

  red[tid] = lb; __syncthreads();
  for (int s = 512; s > 0; s >>= 1) { if (tid < s) red[tid] = fmaxf(red[tid], red[tid+s]); __syncthreads(); }
  const float Mb = red[0]; __syncthreads();
  const float eb = expf(lb - Mb);
  red[tid] = eb; __syncthreads();
  for (int s = 512; s > 0; s >>= 1) { if (tid < s) red[tid] += red[tid+s]; __syncthreads(); }
  const float gb = eb / red[0];

  G[(size_t)(qset*2 + 0)*8192 + b*1024 + tid] = ga;
  G[(size_t)(qset*2 + 1)*8192 + b*1024 + tid] = gb;
}

// ---------------------------------------------------------------------------
// K5: out[b][ch][hw] = gate * V + b128.  ch blocks: [x34 | a_x4 | x43 | b_x3]
// ---------------------------------------------------------------------------
__global__ __launch_bounds__(256) void k5_out(
    const float* __restrict__ V, const float* __restrict__ G,
    const float* __restrict__ b128, float* __restrict__ out)
{
  const int idx = blockIdx.x*256 + threadIdx.x;
  const int flat = idx << 2;
  const int hw = flat & 1023;
  const int ch = (flat >> 10) & 511;
  const int b  = flat >> 19;
  const int blk = ch >> 7, o = ch & 127;
  const int gidx = (blk == 0) ? 2 : (blk == 1) ? 0 : (blk == 2) ? 1 : 3;
  const int src = (blk >= 2) ? 1 : 0;

  const float4 v = *(const float4*)&V[((size_t)((src*8 + b)*128 + o) << 10) + hw];
  const float4 g = *(const float4*)&G[(size_t)gidx*8192 + b*1024 + hw];
  const float bias = b128[o];
  float4 r;
  r.x = g.x*v.x + bias; r.y = g.y*v.y + bias;
  r.z = g.z*v.z + bias; r.w = g.w*v.w + bias;
  *(float4*)&out[flat] = r;
}

// ---------------------------------------------------------------------------
extern "C" void kernel_launch(void* const* d_in, const int* in_sizes, int n_in,
                              void* d_out, int out_size, void* d_ws, size_t ws_size,
                              hipStream_t stream)
{
  const float* x4   = (const float*)d_in[0];
  const float* x3   = (const float*)d_in[1];
  const float* wq   = (const float*)d_in[2];
  const float* bq   = (const float*)d_in[3];
  const float* wk   = (const float*)d_in[4];
  const float* bk   = (const float*)d_in[5];
  const float* wv   = (const float*)d_in[6];
  const float* bv   = (const float*)d_in[7];
  const float* w128 = (const float*)d_in[8];
  const float* b128 = (const float*)d_in[9];
  float* out = (float*)d_out;

  char* ws = (char*)d_ws;
  ushort_t* Qf = (ushort_t*)ws;  ws += (size_t)16384*256*2;     // 8 MB
  ushort_t* Kf = (ushort_t*)ws;  ws += (size_t)16384*256*2;     // 8 MB
  float*    V  = (float*)ws;     ws += (size_t)2*8*128*1024*4;  // 8 MB
  float*    Pt = (float*)ws;     ws += (size_t)128*16384*4;     // 8 MB
  ushort_t* Wf = (ushort_t*)ws;  ws += (size_t)640*256*2;       // 320 KB
  float* bias_all = (float*)ws;  ws += 640*4;
  float*    m2 = (float*)ws;     ws += (size_t)2*16384*4;       // 128 KB
  float*    G  = (float*)ws;                                    // 128 KB

  k1_weights <<<640,   256, 0, stream>>>(wq, bq, wk, bk, wv, bv, w128, b128, Wf, bias_all);
  k2_features<<<256,   256, 0, stream>>>(x4, x3, Wf, bias_all, Qf, Kf, V);
  k3_smax    <<<16384, 256, 0, stream>>>(Qf, Kf, Pt);
  k4a_reduce <<<64,    256, 0, stream>>>(Pt, m2);
  k4b_gates  <<<16,   1024, 0, stream>>>(m2, G);
  k5_out     <<<4096,  256, 0, stream>>>(V, G, b128, out);
}

// Round 3
// 256.982 us; speedup vs baseline: 1.4627x; 1.1235x over previous
//
#include <hip/hip_runtime.h>

typedef unsigned short ushort_t;
typedef __attribute__((ext_vector_type(8))) short bf16x8;
typedef __attribute__((ext_vector_type(4))) float f32x4;

__device__ __forceinline__ unsigned short f2bf(float f) {
  union { float f; unsigned int u; } v; v.f = f;
  unsigned int r = v.u + 0x7FFFu + ((v.u >> 16) & 1u);
  return (unsigned short)(r >> 16);
}

__device__ __forceinline__ void gl_lds16(const void* gsrc, void* ldst) {
  __builtin_amdgcn_global_load_lds(
      (const __attribute__((address_space(1))) void*)gsrc,
      (__attribute__((address_space(3))) void*)ldst, 16, 0, 0);
}

__device__ __forceinline__ f32x4 vmax4(f32x4 a, f32x4 b) {
  f32x4 r;
  r[0] = fmaxf(a[0], b[0]); r[1] = fmaxf(a[1], b[1]);
  r[2] = fmaxf(a[2], b[2]); r[3] = fmaxf(a[3], b[3]);
  return r;
}

// ---------------------------------------------------------------------------
// K1: build fragment-major bf16 weight bank Wf[640][256] (Q=wq, K=wk, V=w128@wv)
//     + bias_all[640] (bq, bk, w128@bv).
// Fragment-major: chunk = (oc>>4)*8 + (ci>>5); lane = ((ci>>3)&3)*16 + (oc&15);
//                 elem = ci&7  -> flat = chunk*512 + lane*8 + elem
// ---------------------------------------------------------------------------
__global__ __launch_bounds__(256) void k1_weights(
    const float* __restrict__ wq, const float* __restrict__ bq,
    const float* __restrict__ wk, const float* __restrict__ bk,
    const float* __restrict__ wv, const float* __restrict__ bv,
    const float* __restrict__ w128,
    ushort_t* __restrict__ Wf, float* __restrict__ bias_all)
{
  const int oc = blockIdx.x;   // 0..639
  const int ci = threadIdx.x;  // 0..255
  float v;
  if (oc < 256)      v = wq[oc*256 + ci];
  else if (oc < 512) v = wk[(oc-256)*256 + ci];
  else {
    float a = 0.f;
    const float* wr = w128 + (size_t)(oc-512)*256;
    for (int co = 0; co < 256; co++) a += wr[co] * wv[co*256 + ci];
    v = a;
  }
  const int idx = (((oc>>4)*8 + (ci>>5))<<9) + ((((ci>>3)&3)*16 + (oc&15))<<3) + (ci&7);
  Wf[idx] = f2bf(v);
  if (ci == 0) {
    float bz;
    if (oc < 256) bz = bq[oc];
    else if (oc < 512) bz = bk[oc-256];
    else {
      float a = 0.f;
      const float* wr = w128 + (size_t)(oc-512)*256;
      for (int co = 0; co < 256; co++) a += wr[co] * bv[co];
      bz = a;
    }
    bias_all[oc] = bz;
  }
}

// ---------------------------------------------------------------------------
// K2: MFMA feature GEMM. Grid 256 blocks = 64-pixel tiles. 4 waves.
//   ot 0..3 -> Qf, 4..7 -> Kf (bf16 frag-major), 8..9 -> V fp32 [src*8+b][oc][hw]
// ---------------------------------------------------------------------------
__global__ __launch_bounds__(256) void k2_features(
    const float* __restrict__ x4, const float* __restrict__ x3,
    const ushort_t* __restrict__ Wf, const float* __restrict__ bias_all,
    ushort_t* __restrict__ Qf, ushort_t* __restrict__ Kf, float* __restrict__ V)
{
  __shared__ ushort_t Af[32*512];      // 32 KB
  __shared__ ushort_t Wl[2][32*512];   // 2 x 32 KB
  __shared__ ushort_t Lt[64*72];       // repack buffer

  const int tid = threadIdx.x;
  const int w = tid >> 6, lane = tid & 63;
  const int mrow = lane & 15, quad = lane >> 4;

  const int px0 = blockIdx.x * 64;
  const int src = px0 >> 13, b = (px0 >> 10) & 7, hw0 = px0 & 1023;
  const float* xp = (src ? x3 : x4) + (size_t)b*262144;

  for (int kb = 0; kb < 8; kb++)
    gl_lds16(Wf + ((size_t)((0*4 + w)*8 + kb)<<9) + lane*8, &Wl[0][(w*8+kb)*512]);

  {
    const int hw = hw0 + w*16 + mrow;
    for (int kb = 0; kb < 8; kb++) {
      const int ch0 = kb*32 + quad*8;
      bf16x8 pk;
      #pragma unroll
      for (int j = 0; j < 8; j++)
        ((ushort_t*)&pk)[j] = f2bf(xp[(size_t)(ch0 + j)*1024 + hw]);
      *(bf16x8*)&Af[(w*8 + kb)*512 + lane*8] = pk;
    }
  }
  __syncthreads();

  for (int ot = 0; ot < 10; ot++) {
    const int nbuf = (ot+1) & 1, cbuf = ot & 1;
    if (ot < 9)
      for (int kb = 0; kb < 8; kb++)
        gl_lds16(Wf + ((size_t)(((ot+1)*4 + w)*8 + kb)<<9) + lane*8,
                 &Wl[nbuf][(w*8+kb)*512]);
    asm volatile("s_waitcnt vmcnt(8)" ::: "memory");

    f32x4 acc[4];
    #pragma unroll
    for (int lg = 0; lg < 4; lg++) acc[lg] = (f32x4){0.f,0.f,0.f,0.f};
    #pragma unroll
    for (int kb = 0; kb < 8; kb++) {
      const bf16x8 a = *(const bf16x8*)&Wl[cbuf][(w*8 + kb)*512 + lane*8];
      #pragma unroll
      for (int lg = 0; lg < 4; lg++) {
        const bf16x8 bx = *(const bf16x8*)&Af[(lg*8 + kb)*512 + lane*8];
        acc[lg] = __builtin_amdgcn_mfma_f32_16x16x32_bf16(a, bx, acc[lg], 0, 0, 0);
      }
    }
    const int ocl = w*16 + quad*4;
    const float4 bias4 = *(const float4*)&bias_all[ot*64 + ocl];

    if (ot < 8) {
      __syncthreads();
      #pragma unroll
      for (int lg = 0; lg < 4; lg++) {
        const int px = lg*16 + mrow;
        ushort4 pk;
        pk.x = f2bf(acc[lg][0] + bias4.x);
        pk.y = f2bf(acc[lg][1] + bias4.y);
        pk.z = f2bf(acc[lg][2] + bias4.z);
        pk.w = f2bf(acc[lg][3] + bias4.w);
        *(ushort4*)&Lt[px*72 + ocl] = pk;
      }
      __syncthreads();
      ushort_t* dst = (ot < 4) ? Qf : Kf;
      const int kbg0 = (ot & 3)*2;
      #pragma unroll
      for (int kbl = 0; kbl < 2; kbl++) {
        const bf16x8 vv = *(const bf16x8*)&Lt[(w*16 + mrow)*72 + kbl*32 + quad*8];
        const size_t chunk = ((size_t)((px0>>4) + w)*8 + kbg0 + kbl) << 9;
        *(bf16x8*)&dst[chunk + lane*8] = vv;
      }
    } else {
      const int ocv0 = (ot-8)*64 + ocl;
      float* vb = V + (((size_t)(src*8 + b)*128) << 10) + hw0;
      #pragma unroll
      for (int lg = 0; lg < 4; lg++) {
        vb[(size_t)(ocv0+0)*1024 + lg*16 + mrow] = acc[lg][0] + bias4.x;
        vb[(size_t)(ocv0+1)*1024 + lg*16 + mrow] = acc[lg][1] + bias4.y;
        vb[(size_t)(ocv0+2)*1024 + lg*16 + mrow] = acc[lg][2] + bias4.z;
        vb[(size_t)(ocv0+3)*1024 + lg*16 + mrow] = acc[lg][3] + bias4.w;
      }
    }
  }
}

// ---------------------------------------------------------------------------
// K3: block = 128 rows x one key-batch (1024 cols).  4 waves (2 wm x 2 wn).
//   Q frags held in registers for the whole block (4 rg x 8 kb = 128 VGPR).
//   K staged via gl_lds, 16 KB double-buffered stages (8 cg x 2 kb), one
//   barrier per stage.  Per-row batch-max folded in-register; one write/row.
//   Pm layout: [batch(16)][row(16384)]
// ---------------------------------------------------------------------------
__global__ __launch_bounds__(256, 2) void k3_smax(
    const ushort_t* __restrict__ Qf, const ushort_t* __restrict__ Kf,
    float* __restrict__ Pm)
{
  __shared__ __align__(16) ushort_t Kl[2][8192];   // 2 x 16 KB

  const int tid = threadIdx.x;
  const int bt = blockIdx.x >> 7;      // key-batch 0..15
  const int rt = blockIdx.x & 127;     // row-tile
  const int w = tid >> 6, lane = tid & 63;
  const int wm = w >> 1, wn = w & 1;
  const int mrow = lane & 15, quad = lane >> 4;

  const int rg0 = rt*8 + wm*4;         // wave's 4 row-groups
  const int cgb = bt*64;               // batch's col-group base (64 cg)

  // prologue: stage (ct=0, s=0): chunks cg 0..7 x kb 0..1; wave w -> slots w*4..+3
  #pragma unroll
  for (int q = 0; q < 4; q++) {
    const int c = w*4 + q;             // slot: cgl = c>>1, kbl = c&1
    gl_lds16(Kf + ((size_t)((cgb + (c>>1))*8 + (c&1))<<9) + lane*8, &Kl[0][c*512]);
  }

  // Q fragments: loaded once, live whole kernel
  bf16x8 qf[4][8];
  #pragma unroll
  for (int i = 0; i < 4; i++)
    #pragma unroll
    for (int kb = 0; kb < 8; kb++)
      qf[i][kb] = *(const bf16x8*)&Qf[((size_t)((rg0 + i)*8 + kb)<<9) + lane*8];

  f32x4 acc[4][4];
  #pragma unroll
  for (int i = 0; i < 4; i++)
    #pragma unroll
    for (int j = 0; j < 4; j++)
      acc[i][j] = (f32x4){0.f, 0.f, 0.f, 0.f};
  f32x4 runmax[4];
  #pragma unroll
  for (int i = 0; i < 4; i++)
    runmax[i] = (f32x4){-3.4e38f, -3.4e38f, -3.4e38f, -3.4e38f};

  for (int ct = 0; ct < 8; ct++) {
    #pragma unroll
    for (int s = 0; s < 4; s++) {
      const int g = ct*4 + s;
      __syncthreads();                 // drains prefetch for stage g
      if (g < 31) {
        const int gn = g + 1, ctn = gn >> 2, sn = gn & 3;
        #pragma unroll
        for (int q = 0; q < 4; q++) {
          const int c = w*4 + q;
          gl_lds16(Kf + ((size_t)((cgb + ctn*8 + (c>>1))*8 + (sn*2 + (c&1)))<<9) + lane*8,
                   &Kl[gn & 1][c*512]);
        }
      }
      const ushort_t* kl = &Kl[g & 1][0];
      #pragma unroll
      for (int kbl = 0; kbl < 2; kbl++) {
        const int kb = s*2 + kbl;
        bf16x8 bfv[4];
        #pragma unroll
        for (int j = 0; j < 4; j++)
          bfv[j] = *(const bf16x8*)&kl[((wn*4 + j)*2 + kbl)*512 + lane*8];
        #pragma unroll
        for (int i = 0; i < 4; i++)
          #pragma unroll
          for (int j = 0; j < 4; j++)
            acc[i][j] = __builtin_amdgcn_mfma_f32_16x16x32_bf16(qf[i][kb], bfv[j], acc[i][j], 0, 0, 0);
      }
    }
    // fold this col-tile into running row-max, re-zero acc
    #pragma unroll
    for (int i = 0; i < 4; i++) {
      runmax[i] = vmax4(runmax[i],
                        vmax4(vmax4(acc[i][0], acc[i][1]), vmax4(acc[i][2], acc[i][3])));
      #pragma unroll
      for (int j = 0; j < 4; j++) acc[i][j] = (f32x4){0.f, 0.f, 0.f, 0.f};
    }
  }

  // epilogue: reduce over 16 cols (lanes), combine wn halves via LDS (overlay Kl[0])
  float* smax = (float*)&Kl[0][0];
  #pragma unroll
  for (int i = 0; i < 4; i++) {
    #pragma unroll
    for (int r = 0; r < 4; r++) {
      float v = runmax[i][r];
      v = fmaxf(v, __shfl_xor(v, 1));
      v = fmaxf(v, __shfl_xor(v, 2));
      v = fmaxf(v, __shfl_xor(v, 4));
      v = fmaxf(v, __shfl_xor(v, 8));
      if (mrow == 0) smax[(wm*64 + i*16 + quad*4 + r)*2 + wn] = v;
    }
  }
  __syncthreads();
  if (tid < 128)
    Pm[(size_t)bt*16384 + rt*128 + tid] = fmaxf(smax[tid*2], smax[tid*2 + 1]);
}

// ---------------------------------------------------------------------------
// K4: per-row logits from batch-maxes + softmax over hw -> gates G[4][8][1024]
// ---------------------------------------------------------------------------
__global__ __launch_bounds__(1024) void k4_gates(
    const float* __restrict__ Pm, float* __restrict__ G)
{
  __shared__ float red[1024];
  const int tid = threadIdx.x;
  const int qset = blockIdx.x >> 3, b = blockIdx.x & 7;
  const int i = qset*8192 + b*1024 + tid;

  float ma = 0.f, mb = 0.f;
  #pragma unroll
  for (int bt = 0; bt < 8; bt++)  ma += Pm[(size_t)bt*16384 + i];
  #pragma unroll
  for (int bt = 8; bt < 16; bt++) mb += Pm[(size_t)bt*16384 + i];
  const float sc = 0.125f * 0.0625f;   // mean over 8 batches * 1/sqrt(256)
  const float la = ma * sc, lb = mb * sc;

  red[tid] = la; __syncthreads();
  for (int s = 512; s > 0; s >>= 1) { if (tid < s) red[tid] = fmaxf(red[tid], red[tid+s]); __syncthreads(); }
  const float Ma = red[0]; __syncthreads();
  const float ea = expf(la - Ma);
  red[tid] = ea; __syncthreads();
  for (int s = 512; s > 0; s >>= 1) { if (tid < s) red[tid] += red[tid+s]; __syncthreads(); }
  const float ga = ea / red[0]; __syncthreads();

  red[tid] = lb; __syncthreads();
  for (int s = 512; s > 0; s >>= 1) { if (tid < s) red[tid] = fmaxf(red[tid], red[tid+s]); __syncthreads(); }
  const float Mb = red[0]; __syncthreads();
  const float eb = expf(lb - Mb);
  red[tid] = eb; __syncthreads();
  for (int s = 512; s > 0; s >>= 1) { if (tid < s) red[tid] += red[tid+s]; __syncthreads(); }
  const float gb = eb / red[0];

  G[(size_t)(qset*2 + 0)*8192 + b*1024 + tid] = ga;
  G[(size_t)(qset*2 + 1)*8192 + b*1024 + tid] = gb;
}

// ---------------------------------------------------------------------------
// K5: out[b][ch][hw] = gate * V + b128.  ch blocks: [x34 | a_x4 | x43 | b_x3]
// ---------------------------------------------------------------------------
__global__ __launch_bounds__(256) void k5_out(
    const float* __restrict__ V, const float* __restrict__ G,
    const float* __restrict__ b128, float* __restrict__ out)
{
  const int idx = blockIdx.x*256 + threadIdx.x;
  const int flat = idx << 2;
  const int hw = flat & 1023;
  const int ch = (flat >> 10) & 511;
  const int b  = flat >> 19;
  const int blk = ch >> 7, o = ch & 127;
  const int gidx = (blk == 0) ? 2 : (blk == 1) ? 0 : (blk == 2) ? 1 : 3;
  const int src = (blk >= 2) ? 1 : 0;

  const float4 v = *(const float4*)&V[((size_t)((src*8 + b)*128 + o) << 10) + hw];
  const float4 g = *(const float4*)&G[(size_t)gidx*8192 + b*1024 + hw];
  const float bias = b128[o];
  float4 r;
  r.x = g.x*v.x + bias; r.y = g.y*v.y + bias;
  r.z = g.z*v.z + bias; r.w = g.w*v.w + bias;
  *(float4*)&out[flat] = r;
}

// ---------------------------------------------------------------------------
extern "C" void kernel_launch(void* const* d_in, const int* in_sizes, int n_in,
                              void* d_out, int out_size, void* d_ws, size_t ws_size,
                              hipStream_t stream)
{
  const float* x4   = (const float*)d_in[0];
  const float* x3   = (const float*)d_in[1];
  const float* wq   = (const float*)d_in[2];
  const float* bq   = (const float*)d_in[3];
  const float* wk   = (const float*)d_in[4];
  const float* bk   = (const float*)d_in[5];
  const float* wv   = (const float*)d_in[6];
  const float* bv   = (const float*)d_in[7];
  const float* w128 = (const float*)d_in[8];
  const float* b128 = (const float*)d_in[9];
  float* out = (float*)d_out;

  char* ws = (char*)d_ws;
  ushort_t* Qf = (ushort_t*)ws;  ws += (size_t)16384*256*2;     // 8 MB
  ushort_t* Kf = (ushort_t*)ws;  ws += (size_t)16384*256*2;     // 8 MB
  float*    V  = (float*)ws;     ws += (size_t)2*8*128*1024*4;  // 8 MB
  float*    Pm = (float*)ws;     ws += (size_t)16*16384*4;      // 1 MB
  ushort_t* Wf = (ushort_t*)ws;  ws += (size_t)640*256*2;       // 320 KB
  float* bias_all = (float*)ws;  ws += 640*4;
  float*    G  = (float*)ws;                                    // 128 KB

  k1_weights <<<640,  256, 0, stream>>>(wq, bq, wk, bk, wv, bv, w128, Wf, bias_all);
  k2_features<<<256,  256, 0, stream>>>(x4, x3, Wf, bias_all, Qf, Kf, V);
  k3_smax    <<<2048, 256, 0, stream>>>(Qf, Kf, Pm);
  k4_gates   <<<16,  1024, 0, stream>>>(Pm, G);
  k5_out     <<<4096, 256, 0, stream>>>(V, G, b128, out);
}

// Round 4
// 232.345 us; speedup vs baseline: 1.6178x; 1.1060x over previous
//
#include <hip/hip_runtime.h>

typedef unsigned short ushort_t;
typedef __attribute__((ext_vector_type(8))) short bf16x8;
typedef __attribute__((ext_vector_type(4))) float f32x4;
typedef __attribute__((ext_vector_type(16))) float f32x16;

__device__ __forceinline__ unsigned short f2bf(float f) {
  union { float f; unsigned int u; } v; v.f = f;
  unsigned int r = v.u + 0x7FFFu + ((v.u >> 16) & 1u);
  return (unsigned short)(r >> 16);
}

__device__ __forceinline__ void gl_lds16(const void* gsrc, void* ldst) {
  __builtin_amdgcn_global_load_lds(
      (const __attribute__((address_space(1))) void*)gsrc,
      (__attribute__((address_space(3))) void*)ldst, 16, 0, 0);
}

__device__ __forceinline__ f32x16 zero16() {
  f32x16 z;
  #pragma unroll
  for (int i = 0; i < 16; i++) z[i] = 0.f;
  return z;
}

// ---------------------------------------------------------------------------
// K1: build fragment-major bf16 weight bank Wf[640][256] (Q=wq, K=wk, V=w128@wv)
//     + bias_all[640].  (16x16x32 frag layout, used only by k2's A operand.)
// ---------------------------------------------------------------------------
__global__ __launch_bounds__(256) void k1_weights(
    const float* __restrict__ wq, const float* __restrict__ bq,
    const float* __restrict__ wk, const float* __restrict__ bk,
    const float* __restrict__ wv, const float* __restrict__ bv,
    const float* __restrict__ w128,
    ushort_t* __restrict__ Wf, float* __restrict__ bias_all)
{
  const int oc = blockIdx.x;   // 0..639
  const int ci = threadIdx.x;  // 0..255
  float v;
  if (oc < 256)      v = wq[oc*256 + ci];
  else if (oc < 512) v = wk[(oc-256)*256 + ci];
  else {
    float a = 0.f;
    const float* wr = w128 + (size_t)(oc-512)*256;
    for (int co = 0; co < 256; co++) a += wr[co] * wv[co*256 + ci];
    v = a;
  }
  const int idx = (((oc>>4)*8 + (ci>>5))<<9) + ((((ci>>3)&3)*16 + (oc&15))<<3) + (ci&7);
  Wf[idx] = f2bf(v);
  if (ci == 0) {
    float bz;
    if (oc < 256) bz = bq[oc];
    else if (oc < 512) bz = bk[oc-256];
    else {
      float a = 0.f;
      const float* wr = w128 + (size_t)(oc-512)*256;
      for (int co = 0; co < 256; co++) a += wr[co] * bv[co];
      bz = a;
    }
    bias_all[oc] = bz;
  }
}

// ---------------------------------------------------------------------------
// K2: MFMA feature GEMM (16x16x32 internally). Grid 256 blocks = 64-px tiles.
//   ot 0..3 -> Qf, 4..7 -> Kf emitted in 32x32x16 A/B-frag layout:
//     frag[lane][j] = X[pg*32 + (lane&31)][kb*16 + (lane>>5)*8 + j]
//   ot 8..9 -> V fp32 [src*8+b][oc][hw]
// ---------------------------------------------------------------------------
__global__ __launch_bounds__(256) void k2_features(
    const float* __restrict__ x4, const float* __restrict__ x3,
    const ushort_t* __restrict__ Wf, const float* __restrict__ bias_all,
    ushort_t* __restrict__ Qf, ushort_t* __restrict__ Kf, float* __restrict__ V)
{
  __shared__ ushort_t Af[32*512];      // 32 KB
  __shared__ ushort_t Wl[2][32*512];   // 2 x 32 KB
  __shared__ ushort_t Lt[64*72];       // repack buffer

  const int tid = threadIdx.x;
  const int w = tid >> 6, lane = tid & 63;
  const int mrow = lane & 15, quad = lane >> 4;
  const int ln31 = lane & 31, half = lane >> 5;

  const int px0 = blockIdx.x * 64;
  const int src = px0 >> 13, b = (px0 >> 10) & 7, hw0 = px0 & 1023;
  const float* xp = (src ? x3 : x4) + (size_t)b*262144;

  for (int kb = 0; kb < 8; kb++)
    gl_lds16(Wf + ((size_t)((0*4 + w)*8 + kb)<<9) + lane*8, &Wl[0][(w*8+kb)*512]);

  {
    const int hw = hw0 + w*16 + mrow;
    for (int kb = 0; kb < 8; kb++) {
      const int ch0 = kb*32 + quad*8;
      bf16x8 pk;
      #pragma unroll
      for (int j = 0; j < 8; j++)
        ((ushort_t*)&pk)[j] = f2bf(xp[(size_t)(ch0 + j)*1024 + hw]);
      *(bf16x8*)&Af[(w*8 + kb)*512 + lane*8] = pk;
    }
  }
  __syncthreads();

  for (int ot = 0; ot < 10; ot++) {
    const int nbuf = (ot+1) & 1, cbuf = ot & 1;
    if (ot < 9)
      for (int kb = 0; kb < 8; kb++)
        gl_lds16(Wf + ((size_t)(((ot+1)*4 + w)*8 + kb)<<9) + lane*8,
                 &Wl[nbuf][(w*8+kb)*512]);
    asm volatile("s_waitcnt vmcnt(8)" ::: "memory");

    f32x4 acc[4];
    #pragma unroll
    for (int lg = 0; lg < 4; lg++) acc[lg] = (f32x4){0.f,0.f,0.f,0.f};
    #pragma unroll
    for (int kb = 0; kb < 8; kb++) {
      const bf16x8 a = *(const bf16x8*)&Wl[cbuf][(w*8 + kb)*512 + lane*8];
      #pragma unroll
      for (int lg = 0; lg < 4; lg++) {
        const bf16x8 bx = *(const bf16x8*)&Af[(lg*8 + kb)*512 + lane*8];
        acc[lg] = __builtin_amdgcn_mfma_f32_16x16x32_bf16(a, bx, acc[lg], 0, 0, 0);
      }
    }
    const int ocl = w*16 + quad*4;
    const float4 bias4 = *(const float4*)&bias_all[ot*64 + ocl];

    if (ot < 8) {
      __syncthreads();
      #pragma unroll
      for (int lg = 0; lg < 4; lg++) {
        const int px = lg*16 + mrow;
        ushort4 pk;
        pk.x = f2bf(acc[lg][0] + bias4.x);
        pk.y = f2bf(acc[lg][1] + bias4.y);
        pk.z = f2bf(acc[lg][2] + bias4.z);
        pk.w = f2bf(acc[lg][3] + bias4.w);
        *(ushort4*)&Lt[px*72 + ocl] = pk;
      }
      __syncthreads();
      // emit 32x32x16 A/B fragments: 8 chunks (pg 0..1 x kbl 0..3), 2 per wave
      ushort_t* dst = (ot < 4) ? Qf : Kf;
      const int kbase = (ot & 3)*4;
      #pragma unroll
      for (int e = 0; e < 2; e++) {
        const int cc = w*2 + e;            // 0..7
        const int pg = cc >> 2, kbl = cc & 3;
        const bf16x8 vv = *(const bf16x8*)&Lt[(pg*32 + ln31)*72 + kbl*16 + half*8];
        const size_t chunk = (size_t)((px0>>5) + pg)*16 + kbase + kbl;
        *(bf16x8*)&dst[(chunk<<9) + lane*8] = vv;
      }
    } else {
      const int ocv0 = (ot-8)*64 + ocl;
      float* vb = V + (((size_t)(src*8 + b)*128) << 10) + hw0;
      #pragma unroll
      for (int lg = 0; lg < 4; lg++) {
        vb[(size_t)(ocv0+0)*1024 + lg*16 + mrow] = acc[lg][0] + bias4.x;
        vb[(size_t)(ocv0+1)*1024 + lg*16 + mrow] = acc[lg][1] + bias4.y;
        vb[(size_t)(ocv0+2)*1024 + lg*16 + mrow] = acc[lg][2] + bias4.z;
        vb[(size_t)(ocv0+3)*1024 + lg*16 + mrow] = acc[lg][3] + bias4.w;
      }
    }
  }
}

// ---------------------------------------------------------------------------
// K3: 32x32x16 MFMA.  Block = 256 rows x one key-batch (1024 cols), 4 waves,
//   wave = 64 rows (2 row-grps of 32), all waves sweep the same cols.
//   Q frags in registers (2x16x4 = 128 VGPR).  K staged via gl_lds in 32 KB
//   double-buffered stages (2 cg32 x 16 kb), 16 barriers/block.
//   Per-row batch-max folded elementwise; one 5-step shuffle reduce at end.
//   Pm layout: [batch(16)][row(16384)]
// ---------------------------------------------------------------------------
__global__ __launch_bounds__(256, 2) void k3_smax(
    const ushort_t* __restrict__ Qf, const ushort_t* __restrict__ Kf,
    float* __restrict__ Pm)
{
  __shared__ __align__(16) ushort_t Kl[2][16384];   // 2 x 32 KB

  const int tid = threadIdx.x;
  const int bt = blockIdx.x >> 6;      // key-batch 0..15
  const int rt = blockIdx.x & 63;      // row-tile (256 rows)
  const int w = tid >> 6, lane = tid & 63;
  const int ln31 = lane & 31, half = lane >> 5;

  const int rgb = rt*8 + w*2;          // wave's first row-grp32
  const int cgb = bt*32;               // batch's col-grp32 base

  // prologue: stage 0 = chunks (cgl 0..1 x kb 0..15); wave w -> chunks w*8..+7
  #pragma unroll
  for (int q = 0; q < 8; q++) {
    const int c = w*8 + q;
    gl_lds16(Kf + ((size_t)((cgb + (c>>4))*16 + (c&15))<<9) + lane*8, &Kl[0][c*512]);
  }

  // Q fragments: loaded once, live whole kernel
  bf16x8 qf[2][16];
  #pragma unroll
  for (int rg = 0; rg < 2; rg++)
    #pragma unroll
    for (int kb = 0; kb < 16; kb++)
      qf[rg][kb] = *(const bf16x8*)&Qf[((size_t)((rgb + rg)*16 + kb)<<9) + lane*8];

  f32x16 rmax0, rmax1;
  #pragma unroll
  for (int i = 0; i < 16; i++) { rmax0[i] = -3.4e38f; rmax1[i] = -3.4e38f; }

  for (int g = 0; g < 16; g++) {
    __syncthreads();                   // drains prefetch for stage g
    if (g < 15) {
      #pragma unroll
      for (int q = 0; q < 8; q++) {
        const int c = w*8 + q;
        gl_lds16(Kf + ((size_t)((cgb + (g+1)*2 + (c>>4))*16 + (c&15))<<9) + lane*8,
                 &Kl[(g+1)&1][c*512]);
      }
    }
    const ushort_t* kl = &Kl[g & 1][0];
    #pragma unroll
    for (int sub = 0; sub < 2; sub++) {
      f32x16 a0 = zero16(), a1 = zero16();
      #pragma unroll
      for (int kb = 0; kb < 16; kb++) {
        const bf16x8 bfv = *(const bf16x8*)&kl[(sub*16 + kb)*512 + lane*8];
        a0 = __builtin_amdgcn_mfma_f32_32x32x16_bf16(qf[0][kb], bfv, a0, 0, 0, 0);
        a1 = __builtin_amdgcn_mfma_f32_32x32x16_bf16(qf[1][kb], bfv, a1, 0, 0, 0);
      }
      #pragma unroll
      for (int i = 0; i < 16; i++) {
        rmax0[i] = fmaxf(rmax0[i], a0[i]);
        rmax1[i] = fmaxf(rmax1[i], a1[i]);
      }
    }
  }

  // epilogue: per-row max over 32 cols (5 xor-shuffles within each 32-lane half)
  // C/D: col = lane&31, row = (reg&3) + 8*(reg>>2) + 4*half  (m74/m101)
  #pragma unroll
  for (int rg = 0; rg < 2; rg++) {
    #pragma unroll
    for (int e = 0; e < 16; e++) {
      float v = (rg == 0) ? rmax0[e] : rmax1[e];
      v = fmaxf(v, __shfl_xor(v, 1));
      v = fmaxf(v, __shfl_xor(v, 2));
      v = fmaxf(v, __shfl_xor(v, 4));
      v = fmaxf(v, __shfl_xor(v, 8));
      v = fmaxf(v, __shfl_xor(v, 16));
      if (ln31 == 0) {
        const int row = rt*256 + w*64 + rg*32 + (e&3) + 8*(e>>2) + 4*half;
        Pm[(size_t)bt*16384 + row] = v;
      }
    }
  }
}

// ---------------------------------------------------------------------------
// K4: per-row logits from batch-maxes + softmax over hw -> gates G[4][8][1024]
// ---------------------------------------------------------------------------
__global__ __launch_bounds__(1024) void k4_gates(
    const float* __restrict__ Pm, float* __restrict__ G)
{
  __shared__ float red[1024];
  const int tid = threadIdx.x;
  const int qset = blockIdx.x >> 3, b = blockIdx.x & 7;
  const int i = qset*8192 + b*1024 + tid;

  float ma = 0.f, mb = 0.f;
  #pragma unroll
  for (int bt = 0; bt < 8; bt++)  ma += Pm[(size_t)bt*16384 + i];
  #pragma unroll
  for (int bt = 8; bt < 16; bt++) mb += Pm[(size_t)bt*16384 + i];
  const float sc = 0.125f * 0.0625f;   // mean over 8 batches * 1/sqrt(256)
  const float la = ma * sc, lb = mb * sc;

  red[tid] = la; __syncthreads();
  for (int s = 512; s > 0; s >>= 1) { if (tid < s) red[tid] = fmaxf(red[tid], red[tid+s]); __syncthreads(); }
  const float Ma = red[0]; __syncthreads();
  const float ea = expf(la - Ma);
  red[tid] = ea; __syncthreads();
  for (int s = 512; s > 0; s >>= 1) { if (tid < s) red[tid] += red[tid+s]; __syncthreads(); }
  const float ga = ea / red[0]; __syncthreads();

  red[tid] = lb; __syncthreads();
  for (int s = 512; s > 0; s >>= 1) { if (tid < s) red[tid] = fmaxf(red[tid], red[tid+s]); __syncthreads(); }
  const float Mb = red[0]; __syncthreads();
  const float eb = expf(lb - Mb);
  red[tid] = eb; __syncthreads();
  for (int s = 512; s > 0; s >>= 1) { if (tid < s) red[tid] += red[tid+s]; __syncthreads(); }
  const float gb = eb / red[0];

  G[(size_t)(qset*2 + 0)*8192 + b*1024 + tid] = ga;
  G[(size_t)(qset*2 + 1)*8192 + b*1024 + tid] = gb;
}

// ---------------------------------------------------------------------------
// K5: out[b][ch][hw] = gate * V + b128.  ch blocks: [x34 | a_x4 | x43 | b_x3]
// ---------------------------------------------------------------------------
__global__ __launch_bounds__(256) void k5_out(
    const float* __restrict__ V, const float* __restrict__ G,
    const float* __restrict__ b128, float* __restrict__ out)
{
  const int idx = blockIdx.x*256 + threadIdx.x;
  const int flat = idx << 2;
  const int hw = flat & 1023;
  const int ch = (flat >> 10) & 511;
  const int b  = flat >> 19;
  const int blk = ch >> 7, o = ch & 127;
  const int gidx = (blk == 0) ? 2 : (blk == 1) ? 0 : (blk == 2) ? 1 : 3;
  const int src = (blk >= 2) ? 1 : 0;

  const float4 v = *(const float4*)&V[((size_t)((src*8 + b)*128 + o) << 10) + hw];
  const float4 g = *(const float4*)&G[(size_t)gidx*8192 + b*1024 + hw];
  const float bias = b128[o];
  float4 r;
  r.x = g.x*v.x + bias; r.y = g.y*v.y + bias;
  r.z = g.z*v.z + bias; r.w = g.w*v.w + bias;
  *(float4*)&out[flat] = r;
}

// ---------------------------------------------------------------------------
extern "C" void kernel_launch(void* const* d_in, const int* in_sizes, int n_in,
                              void* d_out, int out_size, void* d_ws, size_t ws_size,
                              hipStream_t stream)
{
  const float* x4   = (const float*)d_in[0];
  const float* x3   = (const float*)d_in[1];
  const float* wq   = (const float*)d_in[2];
  const float* bq   = (const float*)d_in[3];
  const float* wk   = (const float*)d_in[4];
  const float* bk   = (const float*)d_in[5];
  const float* wv   = (const float*)d_in[6];
  const float* bv   = (const float*)d_in[7];
  const float* w128 = (const float*)d_in[8];
  const float* b128 = (const float*)d_in[9];
  float* out = (float*)d_out;

  char* ws = (char*)d_ws;
  ushort_t* Qf = (ushort_t*)ws;  ws += (size_t)16384*256*2;     // 8 MB
  ushort_t* Kf = (ushort_t*)ws;  ws += (size_t)16384*256*2;     // 8 MB
  float*    V  = (float*)ws;     ws += (size_t)2*8*128*1024*4;  // 8 MB
  float*    Pm = (float*)ws;     ws += (size_t)16*16384*4;      // 1 MB
  ushort_t* Wf = (ushort_t*)ws;  ws += (size_t)640*256*2;       // 320 KB
  float* bias_all = (float*)ws;  ws += 640*4;
  float*    G  = (float*)ws;                                    // 128 KB

  k1_weights <<<640,  256, 0, stream>>>(wq, bq, wk, bk, wv, bv, w128, Wf, bias_all);
  k2_features<<<256,  256, 0, stream>>>(x4, x3, Wf, bias_all, Qf, Kf, V);
  k3_smax    <<<1024, 256, 0, stream>>>(Qf, Kf, Pm);
  k4_gates   <<<16,  1024, 0, stream>>>(Pm, G);
  k5_out     <<<4096, 256, 0, stream>>>(V, G, b128, out);
}